// Round 6
// baseline (641.964 us; speedup 1.0000x reference)
//
#include <hip/hip_runtime.h>
#include <hip/hip_bf16.h>

#define NUSERS 100000
#define NITEMS 50000
#define NNODES 150000
#define EMB 64
#define NLAYERS 3
#define NEDGES 2400000
#define NTILES (NNODES / 16)                                    // 9375
#define NB 293          // buckets of 512 rows: (150000+511)/512
#define EPB (NEDGES / 256)   // 9375 edges per block in stages A/C

typedef __attribute__((ext_vector_type(8))) short short8;
typedef __attribute__((ext_vector_type(4))) float float4v;

__device__ __forceinline__ float bf2f(unsigned short u) {
    return __uint_as_float((unsigned int)u << 16);
}
__device__ __forceinline__ unsigned short f2bf(float f) {
    unsigned int x = __float_as_uint(f);
    return (unsigned short)((x + 0x7FFFu + ((x >> 16) & 1u)) >> 16);   // RNE
}
__device__ __forceinline__ float bfl(unsigned int u) { return __uint_as_float(u << 16); }
__device__ __forceinline__ float bfh(unsigned int u) { return __uint_as_float(u & 0xffff0000u); }

// ---------- CSR build via LDS-only counting sort ----------
// MEASURED HISTORY (do not re-try):
//  - r0/r4: global-atomic hist_rank = 101-106us (HBM random-write granule wall:
//    2.4M device atomics x ~36B write-through).
//  - r3: issuer-side 8-way privatization REGRESSED (+56us): atomics execute at
//    the address-home slice; issuer bucketing localizes nothing.
//  - r5: counting sort @256-thread blocks = ~130us (inferred): 1 block/CU =
//    4 waves/CU on stages A/C/D -> latency-starved. r6: 1024-thread blocks.

// Stage A: per-block LDS histogram over NB buckets -> cnt[bucket*256+block]
__global__ __launch_bounds__(1024) void bucket_count_kernel(
    const int* __restrict__ rows, int* __restrict__ cnt)
{
    __shared__ int hist[NB];
    const int t = threadIdx.x, blk = blockIdx.x;
    for (int i = t; i < NB; i += 1024) hist[i] = 0;
    __syncthreads();
    const int base = blk * EPB;
    for (int i = t; i < EPB; i += 1024)
        atomicAdd(&hist[rows[base + i] >> 9], 1);
    __syncthreads();
    for (int i = t; i < NB; i += 1024) cnt[i * 256 + blk] = hist[i];
}

// Stage B: single-block exclusive scan of cnt[NB*256] (bucket-major), in place.
// 1024 threads, contiguous 74-elem chunks, LDS scan of partials.
#define SCAN_TOT (NB * 256)     // 75008
#define SCAN_CH  74             // 74*1024 >= 75008
__global__ __launch_bounds__(1024) void bucket_scan_kernel(int* __restrict__ cnt)
{
    __shared__ int part[1024];
    const int t = threadIdx.x;
    const int lo = t * SCAN_CH;
    int s = 0;
    for (int i = 0; i < SCAN_CH; ++i) {
        int idx = lo + i;
        if (idx < SCAN_TOT) s += cnt[idx];
    }
    part[t] = s; __syncthreads();
    int v = s;
    for (int off = 1; off < 1024; off <<= 1) {
        int add = (t >= off) ? part[t - off] : 0;
        __syncthreads();
        part[t] += add;
        __syncthreads();
    }
    int run = part[t] - v;              // exclusive prefix of this chunk
    for (int i = 0; i < SCAN_CH; ++i) {
        int idx = lo + i;
        if (idx < SCAN_TOT) {
            int c = cnt[idx];
            cnt[idx] = run;
            run += c;
        }
    }
}

// Stage C: scatter edges into bucket-major staging; pack lrow(9b)<<18 | col(18b).
__global__ __launch_bounds__(1024) void bucket_scatter_kernel(
    const int* __restrict__ rows, const int* __restrict__ cols,
    const float* __restrict__ vals, const int* __restrict__ offs,
    int2* __restrict__ staged)
{
    __shared__ int cur[NB];
    const int t = threadIdx.x, blk = blockIdx.x;
    for (int i = t; i < NB; i += 1024) cur[i] = offs[i * 256 + blk];
    __syncthreads();
    const int base = blk * EPB;
    for (int i = t; i < EPB; i += 1024) {
        int e = base + i;
        int r = rows[e];
        int pos = atomicAdd(&cur[r >> 9], 1);
        staged[pos] = make_int2(((r & 511) << 18) | cols[e], __float_as_int(vals[e]));
    }
}

// Stage D: one block per bucket. LDS deg/scan/cursor over 512 local rows ->
// final row-sorted edges + rowptr. (Order within a row unstable: sum-only use.)
__global__ __launch_bounds__(1024) void bucket_csr_kernel(
    const int* __restrict__ offs, const int2* __restrict__ staged,
    int* __restrict__ rowptr, int2* __restrict__ edges)
{
    __shared__ int deg[512];
    __shared__ int cur[512];
    __shared__ int part[256];
    const int t = threadIdx.x, b = blockIdx.x;
    const int bstart = offs[b * 256];
    const int bend   = (b + 1 < NB) ? offs[(b + 1) * 256] : NEDGES;
    if (t < 512) deg[t] = 0;
    __syncthreads();
    for (int i = bstart + t; i < bend; i += 1024)
        atomicAdd(&deg[staged[i].x >> 18], 1);
    __syncthreads();
    // exclusive scan over 512 (first 256 threads, 2 elems each)
    int d0 = 0, d1 = 0, s = 0;
    if (t < 256) {
        d0 = deg[2 * t]; d1 = deg[2 * t + 1];
        s = d0 + d1;
        part[t] = s;
    }
    __syncthreads();
    int v = s;
    for (int off = 1; off < 256; off <<= 1) {
        int add = (t >= off && t < 256) ? part[t - off] : 0;
        __syncthreads();
        if (t < 256) part[t] += add;
        __syncthreads();
    }
    if (t < 256) {
        int ex = part[t] - v;
        cur[2 * t]     = ex;
        cur[2 * t + 1] = ex + d0;
        int grow = b * 512 + 2 * t;
        if (grow < NNODES)     rowptr[grow]     = bstart + ex;
        if (grow + 1 < NNODES) rowptr[grow + 1] = bstart + ex + d0;
        if (b == 0 && t == 0)  rowptr[NNODES] = NEDGES;
    }
    __syncthreads();
    for (int i = bstart + t; i < bend; i += 1024) {
        int2 se = staged[i];
        int pos = atomicAdd(&cur[se.x >> 18], 1);
        edges[bstart + pos] = make_int2(se.x & 0x3FFFF, se.y);
    }
}

// ---------- weight fp32 -> bf16, TRANSPOSED to [layer][n][k] (once) ----------
__global__ __launch_bounds__(256) void wconv_kernel(
    const float* __restrict__ gw, const float* __restrict__ bw,
    unsigned short* __restrict__ wg_bf, unsigned short* __restrict__ wb_bf)
{
    int i = blockIdx.x * 256 + threadIdx.x;
    if (i >= NLAYERS * EMB * EMB) return;
    int l = i >> 12;
    int k = (i >> 6) & 63;
    int n = i & 63;
    int o = (l << 12) | (n << 6) | k;   // [l][n][k]
    wg_bf[o] = f2bf(gw[i]);
    wb_bf[o] = f2bf(bw[i]);
}

// ---------- ego init (bf16) + output cols 0..63 (fp32) ----------
__global__ __launch_bounds__(256) void init_kernel(
    const float* __restrict__ ue, const float* __restrict__ ie,
    unsigned short* __restrict__ ego_bf, float* __restrict__ out)
{
    int i = blockIdx.x * 256 + threadIdx.x;   // float4 index over NNODES*16
    if (i >= NNODES * 16) return;
    int n = i >> 4, q = i & 15;
    float4 v = (n < NUSERS) ? ((const float4*)ue)[i]
                            : ((const float4*)ie)[i - NUSERS * 16];
    *(float4*)(out + (size_t)n * 256 + q * 4) = v;
    ushort4 b;
    b.x = f2bf(v.x); b.y = f2bf(v.y); b.z = f2bf(v.z); b.w = f2bf(v.w);
    *(ushort4*)(ego_bf + (size_t)n * EMB + q * 4) = b;
}

// ---------- pull-mode SpMM v2 + 4-edge unroll ----------
// One row per 16-lane group; lane cp owns cols cp*4..cp*4+3 (uint2 gather).
// r4 measured: one-row-per-wave + shfl-reduce (v3) was WORSE — keep v2 shape.
// r6: 4 edges / 8 loads in flight (diagnostic for latency- vs BW-bound).
__global__ __launch_bounds__(256) void spmm_pull(
    const int* __restrict__ rowptr, const int2* __restrict__ edges,
    const unsigned short* __restrict__ ego_bf, unsigned short* __restrict__ side_bf)
{
    const int t  = threadIdx.x;
    const int cp = t & 15;                       // col-chunk: cols cp*4..cp*4+3
    const int r  = blockIdx.x * 16 + (t >> 4);   // 16 rows/block, 4/wave
    const int s = rowptr[r], e = rowptr[r + 1];

    float a0 = 0.f, a1 = 0.f, a2 = 0.f, a3 = 0.f;
    float b0 = 0.f, b1 = 0.f, b2 = 0.f, b3 = 0.f;
    int i = s;
    for (; i + 4 <= e; i += 4) {                 // 4 edges, 8 loads in flight
        int2 e0 = edges[i],     e1 = edges[i + 1];
        int2 e2 = edges[i + 2], e3 = edges[i + 3];
        uint2 u0 = *(const uint2*)(ego_bf + (size_t)e0.x * EMB + cp * 4);
        uint2 u1 = *(const uint2*)(ego_bf + (size_t)e1.x * EMB + cp * 4);
        uint2 u2 = *(const uint2*)(ego_bf + (size_t)e2.x * EMB + cp * 4);
        uint2 u3 = *(const uint2*)(ego_bf + (size_t)e3.x * EMB + cp * 4);
        float v0 = __int_as_float(e0.y), v1 = __int_as_float(e1.y);
        float v2 = __int_as_float(e2.y), v3 = __int_as_float(e3.y);
        a0 += v0 * bfl(u0.x); a1 += v0 * bfh(u0.x);
        a2 += v0 * bfl(u0.y); a3 += v0 * bfh(u0.y);
        b0 += v1 * bfl(u1.x); b1 += v1 * bfh(u1.x);
        b2 += v1 * bfl(u1.y); b3 += v1 * bfh(u1.y);
        a0 += v2 * bfl(u2.x); a1 += v2 * bfh(u2.x);
        a2 += v2 * bfl(u2.y); a3 += v2 * bfh(u2.y);
        b0 += v3 * bfl(u3.x); b1 += v3 * bfh(u3.x);
        b2 += v3 * bfl(u3.y); b3 += v3 * bfh(u3.y);
    }
    for (; i < e; ++i) {
        int2 e0 = edges[i];
        float v0 = __int_as_float(e0.y);
        uint2 u0 = *(const uint2*)(ego_bf + (size_t)e0.x * EMB + cp * 4);
        a0 += v0 * bfl(u0.x); a1 += v0 * bfh(u0.x);
        a2 += v0 * bfl(u0.y); a3 += v0 * bfh(u0.y);
    }
    a0 += b0; a1 += b1; a2 += b2; a3 += b3;

    ushort4 o;
    o.x = f2bf(a0); o.y = f2bf(a1); o.z = f2bf(a2); o.w = f2bf(a3);
    *(ushort4*)(side_bf + (size_t)r * EMB + cp * 4) = o;
}

// ---------- MFMA dense: leaky(S@Wg+bg) + leaky((E*S)@Wb+bb), update ego, normalize ----------
// One wave per 16-row tile. 16x16x32 bf16 MFMA:
//   A[m=lane&15][k=(lane>>4)*8+j]; C/D: col=lane&15, row=(lane>>4)*4+reg.
// Weights arrive TRANSPOSED [n][k]: B-fragment = contiguous short8 load.
// NOTE r3: fusing this with SpMM via LDS regressed — keep separate dispatches.
__global__ __launch_bounds__(256) void dense_mfma(
    const unsigned short* __restrict__ side_bf, unsigned short* __restrict__ ego_bf,
    const unsigned short* __restrict__ wg_bf, const unsigned short* __restrict__ wb_bf,
    const float* __restrict__ gb, const float* __restrict__ bb,
    float* __restrict__ out, int out_col0)
{
    const int lane = threadIdx.x & 63;
    const int w    = threadIdx.x >> 6;
    const int m    = lane & 15;     // row (A) / col (B, C)
    const int q    = lane >> 4;     // quad

    const int t = (int)blockIdx.x * 4 + w;     // 16-row tile index
    if (t >= NTILES) return;

    // ---- B fragments: [n0][kh], lane j holds B[k=kh*32+q*8+j][n=n0*16+m]
    short8 bg[4][2], bbf[4][2];
    #pragma unroll
    for (int n0 = 0; n0 < 4; ++n0) {
        const int n = n0 * 16 + m;
        #pragma unroll
        for (int kh = 0; kh < 2; ++kh) {
            bg [n0][kh] = *(const short8*)(wg_bf + n * EMB + kh * 32 + q * 8);
            bbf[n0][kh] = *(const short8*)(wb_bf + n * EMB + kh * 32 + q * 8);
        }
    }
    float bgc[4], bbc[4];
    #pragma unroll
    for (int n0 = 0; n0 < 4; ++n0) { bgc[n0] = gb[n0 * 16 + m]; bbc[n0] = bb[n0 * 16 + m]; }

    // ---- A fragments: rows t*16 .. t*16+15
    const size_t base = (size_t)t * 16 * EMB;
    const int ao = m * EMB + q * 8;
    short8 as0 = *(const short8*)(side_bf + base + ao);
    short8 as1 = *(const short8*)(side_bf + base + ao + 32);
    short8 ae0 = *(const short8*)(ego_bf  + base + ao);
    short8 ae1 = *(const short8*)(ego_bf  + base + ao + 32);
    short8 ap0, ap1;
    #pragma unroll
    for (int jj = 0; jj < 8; ++jj) {
        ap0[jj] = (short)f2bf(bf2f((unsigned short)as0[jj]) * bf2f((unsigned short)ae0[jj]));
        ap1[jj] = (short)f2bf(bf2f((unsigned short)as1[jj]) * bf2f((unsigned short)ae1[jj]));
    }

    // ---- MFMAs
    float4v c1[4], c2[4];
    #pragma unroll
    for (int n0 = 0; n0 < 4; ++n0) { c1[n0] = (float4v)0.f; c2[n0] = (float4v)0.f; }
    #pragma unroll
    for (int n0 = 0; n0 < 4; ++n0) {
        c1[n0] = __builtin_amdgcn_mfma_f32_16x16x32_bf16(as0, bg [n0][0], c1[n0], 0, 0, 0);
        c1[n0] = __builtin_amdgcn_mfma_f32_16x16x32_bf16(as1, bg [n0][1], c1[n0], 0, 0, 0);
        c2[n0] = __builtin_amdgcn_mfma_f32_16x16x32_bf16(ap0, bbf[n0][0], c2[n0], 0, 0, 0);
        c2[n0] = __builtin_amdgcn_mfma_f32_16x16x32_bf16(ap1, bbf[n0][1], c2[n0], 0, 0, 0);
    }

    // ---- epilogue: bias + leaky + ego update + L2 norm
    float eg[4][4];          // [n0][reg]; row = t*16 + q*4 + reg, col = n0*16 + m
    float ss[4] = {0.f, 0.f, 0.f, 0.f};
    #pragma unroll
    for (int n0 = 0; n0 < 4; ++n0) {
        #pragma unroll
        for (int r = 0; r < 4; ++r) {
            float x1 = c1[n0][r] + bgc[n0];
            float x2 = c2[n0][r] + bbc[n0];
            float v1 = x1 > 0.f ? x1 : 0.01f * x1;
            float v2 = x2 > 0.f ? x2 : 0.01f * x2;
            float e = v1 + v2;
            eg[n0][r] = e;
            ss[r] += e * e;
        }
    }
    #pragma unroll
    for (int r = 0; r < 4; ++r) {
        float s = ss[r];
        s += __shfl_xor(s, 1, 64);
        s += __shfl_xor(s, 2, 64);
        s += __shfl_xor(s, 4, 64);
        s += __shfl_xor(s, 8, 64);
        ss[r] = 1.0f / fmaxf(sqrtf(s), 1e-12f);
    }
    #pragma unroll
    for (int r = 0; r < 4; ++r) {
        int row = t * 16 + q * 4 + r;
        #pragma unroll
        for (int n0 = 0; n0 < 4; ++n0) {
            int col = n0 * 16 + m;
            ego_bf[(size_t)row * EMB + col] = f2bf(eg[n0][r]);
            out[(size_t)row * 256 + out_col0 + col] = eg[n0][r] * ss[r];
        }
    }
}

extern "C" void kernel_launch(void* const* d_in, const int* in_sizes, int n_in,
                              void* d_out, int out_size, void* d_ws, size_t ws_size,
                              hipStream_t stream)
{
    const int*   rows = (const int*)  d_in[0];
    const int*   cols = (const int*)  d_in[1];
    const float* vals = (const float*)d_in[2];
    const float* ue   = (const float*)d_in[3];
    const float* ie   = (const float*)d_in[4];
    const float* gw   = (const float*)d_in[5];
    const float* gb   = (const float*)d_in[6];
    const float* bw   = (const float*)d_in[7];
    const float* bb   = (const float*)d_in[8];
    float* out = (float*)d_out;

    // ---- workspace layout (~58.6 MB) ----
    char* p = (char*)d_ws;
    unsigned short* ego_bf  = (unsigned short*)p;  p += (size_t)NNODES * EMB * 2;  // 19.2 MB
    unsigned short* side_bf = (unsigned short*)p;  p += (size_t)NNODES * EMB * 2;  // 19.2 MB
    int2*  edges  = (int2*)p;    p += (size_t)NEDGES * 8;                          // 19.2 MB
    int*   rowptr = (int*)p;     p += ((size_t)NNODES + 4) * 4;                    // 0.6 MB
    unsigned short* wg_bf = (unsigned short*)p;  p += (size_t)NLAYERS * EMB * EMB * 2;
    unsigned short* wb_bf = (unsigned short*)p;  p += (size_t)NLAYERS * EMB * EMB * 2;
    int*   cnt    = (int*)p;     p += (size_t)NB * 256 * 4;                        // 0.3 MB
    // bucket-major staging aliased into side region (19.2 MB == NEDGES*8 exactly;
    // side_bf is first written by layer-0 spmm, after the build completes)
    int2* staged = (int2*)side_bf;

    // ---- CSR build: LDS-only counting sort (no global atomics) ----
    bucket_count_kernel  <<<256, 1024, 0, stream>>>(rows, cnt);
    bucket_scan_kernel   <<<1,   1024, 0, stream>>>(cnt);
    bucket_scatter_kernel<<<256, 1024, 0, stream>>>(rows, cols, vals, cnt, staged);
    bucket_csr_kernel    <<<NB,  1024, 0, stream>>>(cnt, staged, rowptr, edges);

    wconv_kernel<<<(NLAYERS * EMB * EMB + 255) / 256, 256, 0, stream>>>(gw, bw, wg_bf, wb_bf);
    init_kernel<<<(NNODES * 16 + 255) / 256, 256, 0, stream>>>(ue, ie, ego_bf, out);

    for (int l = 0; l < NLAYERS; ++l) {
        spmm_pull<<<NNODES / 16, 256, 0, stream>>>(rowptr, edges, ego_bf, side_bf);
        dense_mfma<<<(NTILES + 3) / 4, 256, 0, stream>>>(
            side_bf, ego_bf,
            wg_bf + l * EMB * EMB, wb_bf + l * EMB * EMB,
            gb + l * EMB, bb + l * EMB,
            out, 64 * (l + 1));
    }
}

// Round 7
// 517.621 us; speedup vs baseline: 1.2402x; 1.2402x over previous
//
#include <hip/hip_runtime.h>
#include <hip/hip_bf16.h>

#define NUSERS 100000
#define NITEMS 50000
#define NNODES 150000
#define EMB 64
#define NLAYERS 3
#define NEDGES 2400000
#define NTILES (NNODES / 16)                                    // 9375
#define NB 293          // buckets of 512 rows: (150000+511)/512
#define EPB (NEDGES / 256)   // 9375 edges per block in stages A/C

typedef __attribute__((ext_vector_type(8))) short short8;
typedef __attribute__((ext_vector_type(4))) float float4v;

__device__ __forceinline__ float bf2f(unsigned short u) {
    return __uint_as_float((unsigned int)u << 16);
}
__device__ __forceinline__ unsigned short f2bf(float f) {
    unsigned int x = __float_as_uint(f);
    return (unsigned short)((x + 0x7FFFu + ((x >> 16) & 1u)) >> 16);   // RNE
}
__device__ __forceinline__ float bfl(unsigned int u) { return __uint_as_float(u << 16); }
__device__ __forceinline__ float bfh(unsigned int u) { return __uint_as_float(u & 0xffff0000u); }

// ---------- CSR build via LDS-only counting sort ----------
// MEASURED HISTORY (do not re-try):
//  - r0/r4: global-atomic hist_rank = 101-106us (HBM random-write granule wall:
//    2.4M device atomics x ~36B write-through).
//  - r3: issuer-side 8-way privatization REGRESSED (+56us): atomics execute at
//    the address-home slice; issuer bucketing localizes nothing.
//  - r5/r6: single-block scan of cnt[75008] = 90-134us MEASURED (one CU,
//    latency-serial; 0.16% occupancy). r7: 3-kernel hierarchical scan.

// Stage A: per-block LDS histogram over NB buckets -> cnt[bucket*256+block]
__global__ __launch_bounds__(1024) void bucket_count_kernel(
    const int* __restrict__ rows, int* __restrict__ cnt)
{
    __shared__ int hist[NB];
    const int t = threadIdx.x, blk = blockIdx.x;
    for (int i = t; i < NB; i += 1024) hist[i] = 0;
    __syncthreads();
    const int base = blk * EPB;
    for (int i = t; i < EPB; i += 1024)
        atomicAdd(&hist[rows[base + i] >> 9], 1);
    __syncthreads();
    for (int i = t; i < NB; i += 1024) cnt[i * 256 + blk] = hist[i];
}

// Stage B1: per-bucket totals (293 blocks x 256 thr, shfl+LDS reduce)
__global__ __launch_bounds__(256) void bucket_sum_kernel(
    const int* __restrict__ cnt, int* __restrict__ bsum)
{
    __shared__ int ws[4];
    const int b = blockIdx.x, t = threadIdx.x;
    int v = cnt[b * 256 + t];
    #pragma unroll
    for (int off = 1; off < 64; off <<= 1) v += __shfl_xor(v, off, 64);
    if ((t & 63) == 0) ws[t >> 6] = v;
    __syncthreads();
    if (t == 0) bsum[b] = ws[0] + ws[1] + ws[2] + ws[3];
}

// Stage B2: exclusive scan of bsum[NB] in place (1 block, all in LDS)
__global__ __launch_bounds__(512) void bucket_base_kernel(int* __restrict__ bsum)
{
    __shared__ int lds[512];
    const int t = threadIdx.x;
    int v = (t < NB) ? bsum[t] : 0;
    lds[t] = v; __syncthreads();
    for (int off = 1; off < 512; off <<= 1) {
        int add = (t >= off) ? lds[t - off] : 0;
        __syncthreads();
        lds[t] += add;
        __syncthreads();
    }
    if (t < NB) bsum[t] = lds[t] - v;   // exclusive prefix
}

// Stage B3: per-bucket exclusive scan of its 256 block-entries + base, in place
__global__ __launch_bounds__(256) void bucket_offs_kernel(
    int* __restrict__ cnt, const int* __restrict__ bsum)
{
    __shared__ int lds[256];
    const int b = blockIdx.x, t = threadIdx.x;
    int v = cnt[b * 256 + t];
    lds[t] = v; __syncthreads();
    for (int off = 1; off < 256; off <<= 1) {
        int add = (t >= off) ? lds[t - off] : 0;
        __syncthreads();
        lds[t] += add;
        __syncthreads();
    }
    cnt[b * 256 + t] = lds[t] - v + bsum[b];
}

// Stage C: scatter edges into bucket-major staging; pack lrow(9b)<<18 | col(18b).
__global__ __launch_bounds__(1024) void bucket_scatter_kernel(
    const int* __restrict__ rows, const int* __restrict__ cols,
    const float* __restrict__ vals, const int* __restrict__ offs,
    int2* __restrict__ staged)
{
    __shared__ int cur[NB];
    const int t = threadIdx.x, blk = blockIdx.x;
    for (int i = t; i < NB; i += 1024) cur[i] = offs[i * 256 + blk];
    __syncthreads();
    const int base = blk * EPB;
    for (int i = t; i < EPB; i += 1024) {
        int e = base + i;
        int r = rows[e];
        int pos = atomicAdd(&cur[r >> 9], 1);
        staged[pos] = make_int2(((r & 511) << 18) | cols[e], __float_as_int(vals[e]));
    }
}

// Stage D: one block per bucket. LDS deg/scan/cursor over 512 local rows ->
// final row-sorted edges + rowptr. (Order within a row unstable: sum-only use.)
__global__ __launch_bounds__(1024) void bucket_csr_kernel(
    const int* __restrict__ offs, const int2* __restrict__ staged,
    int* __restrict__ rowptr, int2* __restrict__ edges)
{
    __shared__ int deg[512];
    __shared__ int cur[512];
    __shared__ int part[256];
    const int t = threadIdx.x, b = blockIdx.x;
    const int bstart = offs[b * 256];
    const int bend   = (b + 1 < NB) ? offs[(b + 1) * 256] : NEDGES;
    if (t < 512) deg[t] = 0;
    __syncthreads();
    for (int i = bstart + t; i < bend; i += 1024)
        atomicAdd(&deg[staged[i].x >> 18], 1);
    __syncthreads();
    // exclusive scan over 512 (first 256 threads, 2 elems each)
    int d0 = 0, d1 = 0, s = 0;
    if (t < 256) {
        d0 = deg[2 * t]; d1 = deg[2 * t + 1];
        s = d0 + d1;
        part[t] = s;
    }
    __syncthreads();
    int v = s;
    for (int off = 1; off < 256; off <<= 1) {
        int add = (t >= off && t < 256) ? part[t - off] : 0;
        __syncthreads();
        if (t < 256) part[t] += add;
        __syncthreads();
    }
    if (t < 256) {
        int ex = part[t] - v;
        cur[2 * t]     = ex;
        cur[2 * t + 1] = ex + d0;
        int grow = b * 512 + 2 * t;
        if (grow < NNODES)     rowptr[grow]     = bstart + ex;
        if (grow + 1 < NNODES) rowptr[grow + 1] = bstart + ex + d0;
        if (b == 0 && t == 0)  rowptr[NNODES] = NEDGES;
    }
    __syncthreads();
    for (int i = bstart + t; i < bend; i += 1024) {
        int2 se = staged[i];
        int pos = atomicAdd(&cur[se.x >> 18], 1);
        edges[bstart + pos] = make_int2(se.x & 0x3FFFF, se.y);
    }
}

// ---------- weight fp32 -> bf16, TRANSPOSED to [layer][n][k] (once) ----------
__global__ __launch_bounds__(256) void wconv_kernel(
    const float* __restrict__ gw, const float* __restrict__ bw,
    unsigned short* __restrict__ wg_bf, unsigned short* __restrict__ wb_bf)
{
    int i = blockIdx.x * 256 + threadIdx.x;
    if (i >= NLAYERS * EMB * EMB) return;
    int l = i >> 12;
    int k = (i >> 6) & 63;
    int n = i & 63;
    int o = (l << 12) | (n << 6) | k;   // [l][n][k]
    wg_bf[o] = f2bf(gw[i]);
    wb_bf[o] = f2bf(bw[i]);
}

// ---------- ego init (bf16) + output cols 0..63 (fp32) ----------
__global__ __launch_bounds__(256) void init_kernel(
    const float* __restrict__ ue, const float* __restrict__ ie,
    unsigned short* __restrict__ ego_bf, float* __restrict__ out)
{
    int i = blockIdx.x * 256 + threadIdx.x;   // float4 index over NNODES*16
    if (i >= NNODES * 16) return;
    int n = i >> 4, q = i & 15;
    float4 v = (n < NUSERS) ? ((const float4*)ue)[i]
                            : ((const float4*)ie)[i - NUSERS * 16];
    *(float4*)(out + (size_t)n * 256 + q * 4) = v;
    ushort4 b;
    b.x = f2bf(v.x); b.y = f2bf(v.y); b.z = f2bf(v.z); b.w = f2bf(v.w);
    *(ushort4*)(ego_bf + (size_t)n * EMB + q * 4) = b;
}

// ---------- pull-mode SpMM v2 + 4-edge unroll ----------
// One row per 16-lane group; lane cp owns cols cp*4..cp*4+3 (uint2 gather).
// r4 measured: one-row-per-wave + shfl-reduce (v3) was WORSE — keep v2 shape.
__global__ __launch_bounds__(256) void spmm_pull(
    const int* __restrict__ rowptr, const int2* __restrict__ edges,
    const unsigned short* __restrict__ ego_bf, unsigned short* __restrict__ side_bf)
{
    const int t  = threadIdx.x;
    const int cp = t & 15;                       // col-chunk: cols cp*4..cp*4+3
    const int r  = blockIdx.x * 16 + (t >> 4);   // 16 rows/block, 4/wave
    const int s = rowptr[r], e = rowptr[r + 1];

    float a0 = 0.f, a1 = 0.f, a2 = 0.f, a3 = 0.f;
    float b0 = 0.f, b1 = 0.f, b2 = 0.f, b3 = 0.f;
    int i = s;
    for (; i + 4 <= e; i += 4) {                 // 4 edges, 8 loads in flight
        int2 e0 = edges[i],     e1 = edges[i + 1];
        int2 e2 = edges[i + 2], e3 = edges[i + 3];
        uint2 u0 = *(const uint2*)(ego_bf + (size_t)e0.x * EMB + cp * 4);
        uint2 u1 = *(const uint2*)(ego_bf + (size_t)e1.x * EMB + cp * 4);
        uint2 u2 = *(const uint2*)(ego_bf + (size_t)e2.x * EMB + cp * 4);
        uint2 u3 = *(const uint2*)(ego_bf + (size_t)e3.x * EMB + cp * 4);
        float v0 = __int_as_float(e0.y), v1 = __int_as_float(e1.y);
        float v2 = __int_as_float(e2.y), v3 = __int_as_float(e3.y);
        a0 += v0 * bfl(u0.x); a1 += v0 * bfh(u0.x);
        a2 += v0 * bfl(u0.y); a3 += v0 * bfh(u0.y);
        b0 += v1 * bfl(u1.x); b1 += v1 * bfh(u1.x);
        b2 += v1 * bfl(u1.y); b3 += v1 * bfh(u1.y);
        a0 += v2 * bfl(u2.x); a1 += v2 * bfh(u2.x);
        a2 += v2 * bfl(u2.y); a3 += v2 * bfh(u2.y);
        b0 += v3 * bfl(u3.x); b1 += v3 * bfh(u3.x);
        b2 += v3 * bfl(u3.y); b3 += v3 * bfh(u3.y);
    }
    for (; i < e; ++i) {
        int2 e0 = edges[i];
        float v0 = __int_as_float(e0.y);
        uint2 u0 = *(const uint2*)(ego_bf + (size_t)e0.x * EMB + cp * 4);
        a0 += v0 * bfl(u0.x); a1 += v0 * bfh(u0.x);
        a2 += v0 * bfl(u0.y); a3 += v0 * bfh(u0.y);
    }
    a0 += b0; a1 += b1; a2 += b2; a3 += b3;

    ushort4 o;
    o.x = f2bf(a0); o.y = f2bf(a1); o.z = f2bf(a2); o.w = f2bf(a3);
    *(ushort4*)(side_bf + (size_t)r * EMB + cp * 4) = o;
}

// ---------- MFMA dense: leaky(S@Wg+bg) + leaky((E*S)@Wb+bb), update ego, normalize ----------
// One wave per 16-row tile. 16x16x32 bf16 MFMA:
//   A[m=lane&15][k=(lane>>4)*8+j]; C/D: col=lane&15, row=(lane>>4)*4+reg.
// Weights arrive TRANSPOSED [n][k]: B-fragment = contiguous short8 load.
// NOTE r3: fusing this with SpMM via LDS regressed — keep separate dispatches.
__global__ __launch_bounds__(256) void dense_mfma(
    const unsigned short* __restrict__ side_bf, unsigned short* __restrict__ ego_bf,
    const unsigned short* __restrict__ wg_bf, const unsigned short* __restrict__ wb_bf,
    const float* __restrict__ gb, const float* __restrict__ bb,
    float* __restrict__ out, int out_col0)
{
    const int lane = threadIdx.x & 63;
    const int w    = threadIdx.x >> 6;
    const int m    = lane & 15;     // row (A) / col (B, C)
    const int q    = lane >> 4;     // quad

    const int t = (int)blockIdx.x * 4 + w;     // 16-row tile index
    if (t >= NTILES) return;

    // ---- B fragments: [n0][kh], lane j holds B[k=kh*32+q*8+j][n=n0*16+m]
    short8 bg[4][2], bbf[4][2];
    #pragma unroll
    for (int n0 = 0; n0 < 4; ++n0) {
        const int n = n0 * 16 + m;
        #pragma unroll
        for (int kh = 0; kh < 2; ++kh) {
            bg [n0][kh] = *(const short8*)(wg_bf + n * EMB + kh * 32 + q * 8);
            bbf[n0][kh] = *(const short8*)(wb_bf + n * EMB + kh * 32 + q * 8);
        }
    }
    float bgc[4], bbc[4];
    #pragma unroll
    for (int n0 = 0; n0 < 4; ++n0) { bgc[n0] = gb[n0 * 16 + m]; bbc[n0] = bb[n0 * 16 + m]; }

    // ---- A fragments: rows t*16 .. t*16+15
    const size_t base = (size_t)t * 16 * EMB;
    const int ao = m * EMB + q * 8;
    short8 as0 = *(const short8*)(side_bf + base + ao);
    short8 as1 = *(const short8*)(side_bf + base + ao + 32);
    short8 ae0 = *(const short8*)(ego_bf  + base + ao);
    short8 ae1 = *(const short8*)(ego_bf  + base + ao + 32);
    short8 ap0, ap1;
    #pragma unroll
    for (int jj = 0; jj < 8; ++jj) {
        ap0[jj] = (short)f2bf(bf2f((unsigned short)as0[jj]) * bf2f((unsigned short)ae0[jj]));
        ap1[jj] = (short)f2bf(bf2f((unsigned short)as1[jj]) * bf2f((unsigned short)ae1[jj]));
    }

    // ---- MFMAs
    float4v c1[4], c2[4];
    #pragma unroll
    for (int n0 = 0; n0 < 4; ++n0) { c1[n0] = (float4v)0.f; c2[n0] = (float4v)0.f; }
    #pragma unroll
    for (int n0 = 0; n0 < 4; ++n0) {
        c1[n0] = __builtin_amdgcn_mfma_f32_16x16x32_bf16(as0, bg [n0][0], c1[n0], 0, 0, 0);
        c1[n0] = __builtin_amdgcn_mfma_f32_16x16x32_bf16(as1, bg [n0][1], c1[n0], 0, 0, 0);
        c2[n0] = __builtin_amdgcn_mfma_f32_16x16x32_bf16(ap0, bbf[n0][0], c2[n0], 0, 0, 0);
        c2[n0] = __builtin_amdgcn_mfma_f32_16x16x32_bf16(ap1, bbf[n0][1], c2[n0], 0, 0, 0);
    }

    // ---- epilogue: bias + leaky + ego update + L2 norm
    float eg[4][4];          // [n0][reg]; row = t*16 + q*4 + reg, col = n0*16 + m
    float ss[4] = {0.f, 0.f, 0.f, 0.f};
    #pragma unroll
    for (int n0 = 0; n0 < 4; ++n0) {
        #pragma unroll
        for (int r = 0; r < 4; ++r) {
            float x1 = c1[n0][r] + bgc[n0];
            float x2 = c2[n0][r] + bbc[n0];
            float v1 = x1 > 0.f ? x1 : 0.01f * x1;
            float v2 = x2 > 0.f ? x2 : 0.01f * x2;
            float e = v1 + v2;
            eg[n0][r] = e;
            ss[r] += e * e;
        }
    }
    #pragma unroll
    for (int r = 0; r < 4; ++r) {
        float s = ss[r];
        s += __shfl_xor(s, 1, 64);
        s += __shfl_xor(s, 2, 64);
        s += __shfl_xor(s, 4, 64);
        s += __shfl_xor(s, 8, 64);
        ss[r] = 1.0f / fmaxf(sqrtf(s), 1e-12f);
    }
    #pragma unroll
    for (int r = 0; r < 4; ++r) {
        int row = t * 16 + q * 4 + r;
        #pragma unroll
        for (int n0 = 0; n0 < 4; ++n0) {
            int col = n0 * 16 + m;
            ego_bf[(size_t)row * EMB + col] = f2bf(eg[n0][r]);
            out[(size_t)row * 256 + out_col0 + col] = eg[n0][r] * ss[r];
        }
    }
}

extern "C" void kernel_launch(void* const* d_in, const int* in_sizes, int n_in,
                              void* d_out, int out_size, void* d_ws, size_t ws_size,
                              hipStream_t stream)
{
    const int*   rows = (const int*)  d_in[0];
    const int*   cols = (const int*)  d_in[1];
    const float* vals = (const float*)d_in[2];
    const float* ue   = (const float*)d_in[3];
    const float* ie   = (const float*)d_in[4];
    const float* gw   = (const float*)d_in[5];
    const float* gb   = (const float*)d_in[6];
    const float* bw   = (const float*)d_in[7];
    const float* bb   = (const float*)d_in[8];
    float* out = (float*)d_out;

    // ---- workspace layout (~58.6 MB) ----
    char* p = (char*)d_ws;
    unsigned short* ego_bf  = (unsigned short*)p;  p += (size_t)NNODES * EMB * 2;  // 19.2 MB
    unsigned short* side_bf = (unsigned short*)p;  p += (size_t)NNODES * EMB * 2;  // 19.2 MB
    int2*  edges  = (int2*)p;    p += (size_t)NEDGES * 8;                          // 19.2 MB
    int*   rowptr = (int*)p;     p += ((size_t)NNODES + 4) * 4;                    // 0.6 MB
    unsigned short* wg_bf = (unsigned short*)p;  p += (size_t)NLAYERS * EMB * EMB * 2;
    unsigned short* wb_bf = (unsigned short*)p;  p += (size_t)NLAYERS * EMB * EMB * 2;
    int*   cnt    = (int*)p;     p += (size_t)NB * 256 * 4;                        // 0.3 MB
    int*   bsum   = (int*)p;     p += (size_t)512 * 4;
    // bucket-major staging aliased into side region (19.2 MB == NEDGES*8 exactly;
    // side_bf is first written by layer-0 spmm, after the build completes)
    int2* staged = (int2*)side_bf;

    // ---- CSR build: LDS-only counting sort (no global atomics) ----
    bucket_count_kernel  <<<256, 1024, 0, stream>>>(rows, cnt);
    bucket_sum_kernel    <<<NB,  256,  0, stream>>>(cnt, bsum);
    bucket_base_kernel   <<<1,   512,  0, stream>>>(bsum);
    bucket_offs_kernel   <<<NB,  256,  0, stream>>>(cnt, bsum);
    bucket_scatter_kernel<<<256, 1024, 0, stream>>>(rows, cols, vals, cnt, staged);
    bucket_csr_kernel    <<<NB,  1024, 0, stream>>>(cnt, staged, rowptr, edges);

    wconv_kernel<<<(NLAYERS * EMB * EMB + 255) / 256, 256, 0, stream>>>(gw, bw, wg_bf, wb_bf);
    init_kernel<<<(NNODES * 16 + 255) / 256, 256, 0, stream>>>(ue, ie, ego_bf, out);

    for (int l = 0; l < NLAYERS; ++l) {
        spmm_pull<<<NNODES / 16, 256, 0, stream>>>(rowptr, edges, ego_bf, side_bf);
        dense_mfma<<<(NTILES + 3) / 4, 256, 0, stream>>>(
            side_bf, ego_bf,
            wg_bf + l * EMB * EMB, wb_bf + l * EMB * EMB,
            gb + l * EMB, bb + l * EMB,
            out, 64 * (l + 1));
    }
}

// Round 8
// 515.116 us; speedup vs baseline: 1.2463x; 1.0049x over previous
//
#include <hip/hip_runtime.h>
#include <hip/hip_bf16.h>

#define NUSERS 100000
#define NITEMS 50000
#define NNODES 150000
#define EMB 64
#define NLAYERS 3
#define NEDGES 2400000
#define NTILES (NNODES / 16)                                    // 9375
#define NB 293          // buckets of 512 rows: (150000+511)/512
#define EPB (NEDGES / 256)   // 9375 edges per block in stages A/C
#define WCONV_BLOCKS ((NLAYERS * EMB * EMB + 255) / 256)        // 48
#define INIT_BLOCKS  ((NNODES * 16 + 255) / 256)                // 9375

typedef __attribute__((ext_vector_type(8))) short short8;
typedef __attribute__((ext_vector_type(4))) float float4v;

__device__ __forceinline__ float bf2f(unsigned short u) {
    return __uint_as_float((unsigned int)u << 16);
}
__device__ __forceinline__ unsigned short f2bf(float f) {
    unsigned int x = __float_as_uint(f);
    return (unsigned short)((x + 0x7FFFu + ((x >> 16) & 1u)) >> 16);   // RNE
}
__device__ __forceinline__ float bfl(unsigned int u) { return __uint_as_float(u << 16); }
__device__ __forceinline__ float bfh(unsigned int u) { return __uint_as_float(u & 0xffff0000u); }

// ---------- CSR build via LDS-only counting sort ----------
// MEASURED HISTORY (do not re-try):
//  - r0/r4: global-atomic hist_rank = 101-106us (HBM random-write granule wall:
//    2.4M returning device atomics x ~36B write-through).
//  - r3: issuer-side 8-way privatization REGRESSED (+56us): atomics execute at
//    the address-home slice; issuer bucketing localizes nothing.
//  - r5/r6: single-block scan of cnt[75008] = 90-134us MEASURED (one CU,
//    latency-serial). r7 hierarchical 3-kernel scan: 642 -> 517us total.

// Stage A: per-block LDS histogram over NB buckets -> cnt[bucket*256+block]
__global__ __launch_bounds__(1024) void bucket_count_kernel(
    const int* __restrict__ rows, int* __restrict__ cnt)
{
    __shared__ int hist[NB];
    const int t = threadIdx.x, blk = blockIdx.x;
    for (int i = t; i < NB; i += 1024) hist[i] = 0;
    __syncthreads();
    const int base = blk * EPB;
    for (int i = t; i < EPB; i += 1024)
        atomicAdd(&hist[rows[base + i] >> 9], 1);
    __syncthreads();
    for (int i = t; i < NB; i += 1024) cnt[i * 256 + blk] = hist[i];
}

// Stage B1: per-bucket totals (293 blocks x 256 thr, shfl+LDS reduce)
__global__ __launch_bounds__(256) void bucket_sum_kernel(
    const int* __restrict__ cnt, int* __restrict__ bsum)
{
    __shared__ int ws[4];
    const int b = blockIdx.x, t = threadIdx.x;
    int v = cnt[b * 256 + t];
    #pragma unroll
    for (int off = 1; off < 64; off <<= 1) v += __shfl_xor(v, off, 64);
    if ((t & 63) == 0) ws[t >> 6] = v;
    __syncthreads();
    if (t == 0) bsum[b] = ws[0] + ws[1] + ws[2] + ws[3];
}

// Stage B2: exclusive scan of bsum[NB] in place (1 block, all in LDS)
__global__ __launch_bounds__(512) void bucket_base_kernel(int* __restrict__ bsum)
{
    __shared__ int lds[512];
    const int t = threadIdx.x;
    int v = (t < NB) ? bsum[t] : 0;
    lds[t] = v; __syncthreads();
    for (int off = 1; off < 512; off <<= 1) {
        int add = (t >= off) ? lds[t - off] : 0;
        __syncthreads();
        lds[t] += add;
        __syncthreads();
    }
    if (t < NB) bsum[t] = lds[t] - v;   // exclusive prefix
}

// Stage B3: per-bucket exclusive scan of its 256 block-entries + base, in place
__global__ __launch_bounds__(256) void bucket_offs_kernel(
    int* __restrict__ cnt, const int* __restrict__ bsum)
{
    __shared__ int lds[256];
    const int b = blockIdx.x, t = threadIdx.x;
    int v = cnt[b * 256 + t];
    lds[t] = v; __syncthreads();
    for (int off = 1; off < 256; off <<= 1) {
        int add = (t >= off) ? lds[t - off] : 0;
        __syncthreads();
        lds[t] += add;
        __syncthreads();
    }
    cnt[b * 256 + t] = lds[t] - v + bsum[b];
}

// Stage C: scatter edges into bucket-major staging; pack lrow(9b)<<18 | col(18b).
__global__ __launch_bounds__(1024) void bucket_scatter_kernel(
    const int* __restrict__ rows, const int* __restrict__ cols,
    const float* __restrict__ vals, const int* __restrict__ offs,
    int2* __restrict__ staged)
{
    __shared__ int cur[NB];
    const int t = threadIdx.x, blk = blockIdx.x;
    for (int i = t; i < NB; i += 1024) cur[i] = offs[i * 256 + blk];
    __syncthreads();
    const int base = blk * EPB;
    for (int i = t; i < EPB; i += 1024) {
        int e = base + i;
        int r = rows[e];
        int pos = atomicAdd(&cur[r >> 9], 1);
        staged[pos] = make_int2(((r & 511) << 18) | cols[e], __float_as_int(vals[e]));
    }
}

// Stage D: one block per bucket. LDS deg/scan/cursor over 512 local rows ->
// final row-sorted edges + rowptr. (Order within a row unstable: sum-only use.)
__global__ __launch_bounds__(1024) void bucket_csr_kernel(
    const int* __restrict__ offs, const int2* __restrict__ staged,
    int* __restrict__ rowptr, int2* __restrict__ edges)
{
    __shared__ int deg[512];
    __shared__ int cur[512];
    __shared__ int part[256];
    const int t = threadIdx.x, b = blockIdx.x;
    const int bstart = offs[b * 256];
    const int bend   = (b + 1 < NB) ? offs[(b + 1) * 256] : NEDGES;
    if (t < 512) deg[t] = 0;
    __syncthreads();
    for (int i = bstart + t; i < bend; i += 1024)
        atomicAdd(&deg[staged[i].x >> 18], 1);
    __syncthreads();
    // exclusive scan over 512 (first 256 threads, 2 elems each)
    int d0 = 0, d1 = 0, s = 0;
    if (t < 256) {
        d0 = deg[2 * t]; d1 = deg[2 * t + 1];
        s = d0 + d1;
        part[t] = s;
    }
    __syncthreads();
    int v = s;
    for (int off = 1; off < 256; off <<= 1) {
        int add = (t >= off && t < 256) ? part[t - off] : 0;
        __syncthreads();
        if (t < 256) part[t] += add;
        __syncthreads();
    }
    if (t < 256) {
        int ex = part[t] - v;
        cur[2 * t]     = ex;
        cur[2 * t + 1] = ex + d0;
        int grow = b * 512 + 2 * t;
        if (grow < NNODES)     rowptr[grow]     = bstart + ex;
        if (grow + 1 < NNODES) rowptr[grow + 1] = bstart + ex + d0;
        if (b == 0 && t == 0)  rowptr[NNODES] = NEDGES;
    }
    __syncthreads();
    for (int i = bstart + t; i < bend; i += 1024) {
        int2 se = staged[i];
        int pos = atomicAdd(&cur[se.x >> 18], 1);
        edges[bstart + pos] = make_int2(se.x & 0x3FFFF, se.y);
    }
}

// ---------- fused: weight fp32->bf16 transpose [l][n][k]  +  ego init ----------
// blocks [0, WCONV_BLOCKS): wconv; blocks [WCONV_BLOCKS, +INIT_BLOCKS): init.
__global__ __launch_bounds__(256) void wconv_init_kernel(
    const float* __restrict__ gw, const float* __restrict__ bw,
    unsigned short* __restrict__ wg_bf, unsigned short* __restrict__ wb_bf,
    const float* __restrict__ ue, const float* __restrict__ ie,
    unsigned short* __restrict__ ego_bf, float* __restrict__ out)
{
    if (blockIdx.x < WCONV_BLOCKS) {
        int i = blockIdx.x * 256 + threadIdx.x;
        if (i >= NLAYERS * EMB * EMB) return;
        int l = i >> 12;
        int k = (i >> 6) & 63;
        int n = i & 63;
        int o = (l << 12) | (n << 6) | k;   // [l][n][k]
        wg_bf[o] = f2bf(gw[i]);
        wb_bf[o] = f2bf(bw[i]);
        return;
    }
    int i = (blockIdx.x - WCONV_BLOCKS) * 256 + threadIdx.x;  // float4 idx
    if (i >= NNODES * 16) return;
    int n = i >> 4, q = i & 15;
    float4 v = (n < NUSERS) ? ((const float4*)ue)[i]
                            : ((const float4*)ie)[i - NUSERS * 16];
    *(float4*)(out + (size_t)n * 256 + q * 4) = v;
    ushort4 b;
    b.x = f2bf(v.x); b.y = f2bf(v.y); b.z = f2bf(v.z); b.w = f2bf(v.w);
    *(ushort4*)(ego_bf + (size_t)n * EMB + q * 4) = b;
}

// ---------- pull-mode SpMM v2 + 4-edge unroll, occupancy-pinned ----------
// One row per 16-lane group; lane cp owns cols cp*4..cp*4+3 (uint2 gather).
// r4 measured: one-row-per-wave + shfl-reduce (v3) WORSE — keep v2 shape.
// r3 measured: spmm throughput scales with occupancy (fused@10 waves/CU was
// ~30% slower on identical gather work). r8: __launch_bounds__(256,8) pins
// VGPR<=64 so the 4-edge unroll cannot cross the 64-VGPR occupancy cliff.
__global__ __launch_bounds__(256, 8) void spmm_pull(
    const int* __restrict__ rowptr, const int2* __restrict__ edges,
    const unsigned short* __restrict__ ego_bf, unsigned short* __restrict__ side_bf)
{
    const int t  = threadIdx.x;
    const int cp = t & 15;                       // col-chunk: cols cp*4..cp*4+3
    const int r  = blockIdx.x * 16 + (t >> 4);   // 16 rows/block, 4/wave
    const int s = rowptr[r], e = rowptr[r + 1];

    float a0 = 0.f, a1 = 0.f, a2 = 0.f, a3 = 0.f;
    float b0 = 0.f, b1 = 0.f, b2 = 0.f, b3 = 0.f;
    int i = s;
    for (; i + 4 <= e; i += 4) {                 // 4 edges, 8 loads in flight
        int2 e0 = edges[i],     e1 = edges[i + 1];
        int2 e2 = edges[i + 2], e3 = edges[i + 3];
        uint2 u0 = *(const uint2*)(ego_bf + (size_t)e0.x * EMB + cp * 4);
        uint2 u1 = *(const uint2*)(ego_bf + (size_t)e1.x * EMB + cp * 4);
        uint2 u2 = *(const uint2*)(ego_bf + (size_t)e2.x * EMB + cp * 4);
        uint2 u3 = *(const uint2*)(ego_bf + (size_t)e3.x * EMB + cp * 4);
        float v0 = __int_as_float(e0.y), v1 = __int_as_float(e1.y);
        float v2 = __int_as_float(e2.y), v3 = __int_as_float(e3.y);
        a0 += v0 * bfl(u0.x); a1 += v0 * bfh(u0.x);
        a2 += v0 * bfl(u0.y); a3 += v0 * bfh(u0.y);
        b0 += v1 * bfl(u1.x); b1 += v1 * bfh(u1.x);
        b2 += v1 * bfl(u1.y); b3 += v1 * bfh(u1.y);
        a0 += v2 * bfl(u2.x); a1 += v2 * bfh(u2.x);
        a2 += v2 * bfl(u2.y); a3 += v2 * bfh(u2.y);
        b0 += v3 * bfl(u3.x); b1 += v3 * bfh(u3.x);
        b2 += v3 * bfl(u3.y); b3 += v3 * bfh(u3.y);
    }
    for (; i < e; ++i) {
        int2 e0 = edges[i];
        float v0 = __int_as_float(e0.y);
        uint2 u0 = *(const uint2*)(ego_bf + (size_t)e0.x * EMB + cp * 4);
        a0 += v0 * bfl(u0.x); a1 += v0 * bfh(u0.x);
        a2 += v0 * bfl(u0.y); a3 += v0 * bfh(u0.y);
    }
    a0 += b0; a1 += b1; a2 += b2; a3 += b3;

    ushort4 o;
    o.x = f2bf(a0); o.y = f2bf(a1); o.z = f2bf(a2); o.w = f2bf(a3);
    *(ushort4*)(side_bf + (size_t)r * EMB + cp * 4) = o;
}

// ---------- MFMA dense: leaky(S@Wg+bg) + leaky((E*S)@Wb+bb), update ego, normalize ----------
// One wave per 16-row tile. 16x16x32 bf16 MFMA:
//   A[m=lane&15][k=(lane>>4)*8+j]; C/D: col=lane&15, row=(lane>>4)*4+reg.
// Weights arrive TRANSPOSED [n][k]: B-fragment = contiguous short8 load.
// NOTE r3: fusing this with SpMM via LDS regressed — keep separate dispatches.
__global__ __launch_bounds__(256) void dense_mfma(
    const unsigned short* __restrict__ side_bf, unsigned short* __restrict__ ego_bf,
    const unsigned short* __restrict__ wg_bf, const unsigned short* __restrict__ wb_bf,
    const float* __restrict__ gb, const float* __restrict__ bb,
    float* __restrict__ out, int out_col0)
{
    const int lane = threadIdx.x & 63;
    const int w    = threadIdx.x >> 6;
    const int m    = lane & 15;     // row (A) / col (B, C)
    const int q    = lane >> 4;     // quad

    const int t = (int)blockIdx.x * 4 + w;     // 16-row tile index
    if (t >= NTILES) return;

    // ---- B fragments: [n0][kh], lane j holds B[k=kh*32+q*8+j][n=n0*16+m]
    short8 bg[4][2], bbf[4][2];
    #pragma unroll
    for (int n0 = 0; n0 < 4; ++n0) {
        const int n = n0 * 16 + m;
        #pragma unroll
        for (int kh = 0; kh < 2; ++kh) {
            bg [n0][kh] = *(const short8*)(wg_bf + n * EMB + kh * 32 + q * 8);
            bbf[n0][kh] = *(const short8*)(wb_bf + n * EMB + kh * 32 + q * 8);
        }
    }
    float bgc[4], bbc[4];
    #pragma unroll
    for (int n0 = 0; n0 < 4; ++n0) { bgc[n0] = gb[n0 * 16 + m]; bbc[n0] = bb[n0 * 16 + m]; }

    // ---- A fragments: rows t*16 .. t*16+15
    const size_t base = (size_t)t * 16 * EMB;
    const int ao = m * EMB + q * 8;
    short8 as0 = *(const short8*)(side_bf + base + ao);
    short8 as1 = *(const short8*)(side_bf + base + ao + 32);
    short8 ae0 = *(const short8*)(ego_bf  + base + ao);
    short8 ae1 = *(const short8*)(ego_bf  + base + ao + 32);
    short8 ap0, ap1;
    #pragma unroll
    for (int jj = 0; jj < 8; ++jj) {
        ap0[jj] = (short)f2bf(bf2f((unsigned short)as0[jj]) * bf2f((unsigned short)ae0[jj]));
        ap1[jj] = (short)f2bf(bf2f((unsigned short)as1[jj]) * bf2f((unsigned short)ae1[jj]));
    }

    // ---- MFMAs
    float4v c1[4], c2[4];
    #pragma unroll
    for (int n0 = 0; n0 < 4; ++n0) { c1[n0] = (float4v)0.f; c2[n0] = (float4v)0.f; }
    #pragma unroll
    for (int n0 = 0; n0 < 4; ++n0) {
        c1[n0] = __builtin_amdgcn_mfma_f32_16x16x32_bf16(as0, bg [n0][0], c1[n0], 0, 0, 0);
        c1[n0] = __builtin_amdgcn_mfma_f32_16x16x32_bf16(as1, bg [n0][1], c1[n0], 0, 0, 0);
        c2[n0] = __builtin_amdgcn_mfma_f32_16x16x32_bf16(ap0, bbf[n0][0], c2[n0], 0, 0, 0);
        c2[n0] = __builtin_amdgcn_mfma_f32_16x16x32_bf16(ap1, bbf[n0][1], c2[n0], 0, 0, 0);
    }

    // ---- epilogue: bias + leaky + ego update + L2 norm
    float eg[4][4];          // [n0][reg]; row = t*16 + q*4 + reg, col = n0*16 + m
    float ss[4] = {0.f, 0.f, 0.f, 0.f};
    #pragma unroll
    for (int n0 = 0; n0 < 4; ++n0) {
        #pragma unroll
        for (int r = 0; r < 4; ++r) {
            float x1 = c1[n0][r] + bgc[n0];
            float x2 = c2[n0][r] + bbc[n0];
            float v1 = x1 > 0.f ? x1 : 0.01f * x1;
            float v2 = x2 > 0.f ? x2 : 0.01f * x2;
            float e = v1 + v2;
            eg[n0][r] = e;
            ss[r] += e * e;
        }
    }
    #pragma unroll
    for (int r = 0; r < 4; ++r) {
        float s = ss[r];
        s += __shfl_xor(s, 1, 64);
        s += __shfl_xor(s, 2, 64);
        s += __shfl_xor(s, 4, 64);
        s += __shfl_xor(s, 8, 64);
        ss[r] = 1.0f / fmaxf(sqrtf(s), 1e-12f);
    }
    #pragma unroll
    for (int r = 0; r < 4; ++r) {
        int row = t * 16 + q * 4 + r;
        #pragma unroll
        for (int n0 = 0; n0 < 4; ++n0) {
            int col = n0 * 16 + m;
            ego_bf[(size_t)row * EMB + col] = f2bf(eg[n0][r]);
            out[(size_t)row * 256 + out_col0 + col] = eg[n0][r] * ss[r];
        }
    }
}

extern "C" void kernel_launch(void* const* d_in, const int* in_sizes, int n_in,
                              void* d_out, int out_size, void* d_ws, size_t ws_size,
                              hipStream_t stream)
{
    const int*   rows = (const int*)  d_in[0];
    const int*   cols = (const int*)  d_in[1];
    const float* vals = (const float*)d_in[2];
    const float* ue   = (const float*)d_in[3];
    const float* ie   = (const float*)d_in[4];
    const float* gw   = (const float*)d_in[5];
    const float* gb   = (const float*)d_in[6];
    const float* bw   = (const float*)d_in[7];
    const float* bb   = (const float*)d_in[8];
    float* out = (float*)d_out;

    // ---- workspace layout (~58.6 MB) ----
    char* p = (char*)d_ws;
    unsigned short* ego_bf  = (unsigned short*)p;  p += (size_t)NNODES * EMB * 2;  // 19.2 MB
    unsigned short* side_bf = (unsigned short*)p;  p += (size_t)NNODES * EMB * 2;  // 19.2 MB
    int2*  edges  = (int2*)p;    p += (size_t)NEDGES * 8;                          // 19.2 MB
    int*   rowptr = (int*)p;     p += ((size_t)NNODES + 4) * 4;                    // 0.6 MB
    unsigned short* wg_bf = (unsigned short*)p;  p += (size_t)NLAYERS * EMB * EMB * 2;
    unsigned short* wb_bf = (unsigned short*)p;  p += (size_t)NLAYERS * EMB * EMB * 2;
    int*   cnt    = (int*)p;     p += (size_t)NB * 256 * 4;                        // 0.3 MB
    int*   bsum   = (int*)p;     p += (size_t)512 * 4;
    // bucket-major staging aliased into side region (19.2 MB == NEDGES*8 exactly;
    // side_bf is first written by layer-0 spmm, after the build completes)
    int2* staged = (int2*)side_bf;

    // ---- CSR build: LDS-only counting sort (no global atomics) ----
    bucket_count_kernel  <<<256, 1024, 0, stream>>>(rows, cnt);
    bucket_sum_kernel    <<<NB,  256,  0, stream>>>(cnt, bsum);
    bucket_base_kernel   <<<1,   512,  0, stream>>>(bsum);
    bucket_offs_kernel   <<<NB,  256,  0, stream>>>(cnt, bsum);
    bucket_scatter_kernel<<<256, 1024, 0, stream>>>(rows, cols, vals, cnt, staged);
    bucket_csr_kernel    <<<NB,  1024, 0, stream>>>(cnt, staged, rowptr, edges);

    wconv_init_kernel<<<WCONV_BLOCKS + INIT_BLOCKS, 256, 0, stream>>>(
        gw, bw, wg_bf, wb_bf, ue, ie, ego_bf, out);

    for (int l = 0; l < NLAYERS; ++l) {
        spmm_pull<<<NNODES / 16, 256, 0, stream>>>(rowptr, edges, ego_bf, side_bf);
        dense_mfma<<<(NTILES + 3) / 4, 256, 0, stream>>>(
            side_bf, ego_bf,
            wg_bf + l * EMB * EMB, wb_bf + l * EMB * EMB,
            gb + l * EMB, bb + l * EMB,
            out, 64 * (l + 1));
    }
}